// Round 12
// baseline (506.523 us; speedup 1.0000x reference)
//
#include <hip/hip_runtime.h>
#include <hip/hip_bf16.h>
#include <stdint.h>

// GCN pose: fused per-sample chain. 64*243=15552 samples, 17 joints, hidden 256, 4 layers.
// Round 12: occupancy push — single h buffer (in-place pointwise, 2 barriers/layer),
// LDS 52 KB -> 3 WG/CU; acc reused as mix accumulator (32-reg accumulator footprint);
// __launch_bounds__(512,6) targets 6 waves/SIMD. Math identical to round 11
// (single-pass bf16 W GEMM, exact hi/lo Ahat MFMA mix, fenced liveness).

#define J17   17
#define HID   256
#define NLAY  4
#define NSAMP 15552
#define SPW   3
#define RUSE  51         // SPW*17 used rows
#define RPAD  64         // padded rows (2 row-tiles of 32)
#define NWG   5184       // NSAMP/SPW exactly

typedef __attribute__((ext_vector_type(4)))  short  short4v;
typedef __attribute__((ext_vector_type(8)))  short  short8;
typedef __attribute__((ext_vector_type(16))) float  float16;

__device__ __forceinline__ unsigned short f2bf(float f){
  return __bfloat16_as_ushort(__float2bfloat16(f));   // v_cvt, RNE
}
__device__ __forceinline__ float bf2f(unsigned short b){
  return __builtin_bit_cast(float, ((unsigned)b) << 16);
}

// ---------------- prep ----------------
// pret_b (512 KB): [t(64)][kh(2)][c(256)][j(8)], value = bf16(W[t>>4][k][c]),
//                k = (t&15)*16 + kh*8 + j
// pret_in (8 KB): [kh(2)][c(256)][j(8)] = bf16(w_in[k][c]), k = kh*8+j (<3 else 0)
// pret_out (32 KB): [hl(2)][ks(16)][kh(2)][col(32)][j(8)] = split(w_out[k][col], hl)
// pret_a (16 KB): [rt(2)][ks(4)][hl(2)][lane(64)][j(8)] = split(Ahat_bd[R][K], hl),
//                R = rt*32 + (lane&31), K = ks*16 + (lane>>5)*8 + j
__global__ __launch_bounds__(256)
void gcn_prep(const float* __restrict__ adj, const float* __restrict__ Ws,
              const float* __restrict__ w_in, const float* __restrict__ w_out,
              unsigned short* __restrict__ pret_a, unsigned short* __restrict__ pret_in,
              unsigned short* __restrict__ pret_out, unsigned short* __restrict__ pret_b)
{
  if (blockIdx.x < 1024){
    const int e  = blockIdx.x*256 + threadIdx.x;
    const int j  = e & 7, cc = (e >> 3) & 255, khh = (e >> 11) & 1, t = e >> 12;
    const int k  = (t & 15)*16 + khh*8 + j;
    pret_b[(t*2 + khh)*2048 + cc*8 + j] = f2bf(Ws[(t >> 4)*65536 + k*256 + cc]);
  } else {
    const int tid = threadIdx.x;
    __shared__ float Ash[289];
    for (int t = tid; t < 289; t += 256){
      const int j = t/17, k2 = t%17;
      float dj = 1e-5f, dk = 1e-5f;
      for (int m=0;m<17;++m){ dj += adj[j*17+m]; dk += adj[k2*17+m]; }
      Ash[t] = adj[t] / (sqrtf(dj)*sqrtf(dk));
    }
    __syncthreads();
    for (int e = tid; e < 4096; e += 256){
      const int j = e & 7, cc = (e >> 3) & 255, khh = e >> 11;
      const int k = khh*8 + j;
      pret_in[e] = (k < 3) ? f2bf(w_in[k*256 + cc]) : (unsigned short)0;
    }
    for (int e = tid; e < 8192; e += 256){
      const int j = e & 7, col = (e >> 3) & 31, khh = (e >> 8) & 1, ks = e >> 9;
      const int k = ks*16 + khh*8 + j;
      const float w = (col < 3) ? w_out[k*3 + col] : 0.0f;
      const unsigned short hi = f2bf(w);
      const int idx = ((ks*2 + khh)*32 + col)*8 + j;
      pret_out[idx]        = hi;
      pret_out[idx + 8192] = f2bf(w - bf2f(hi));
    }
    // Ahat_bd fragments (hi/lo split keeps the graph mix exact)
    for (int e = tid; e < 8192; e += 256){
      const int j = e & 7, lane = (e >> 3) & 63, hl = (e >> 9) & 1;
      const int ks = (e >> 10) & 3, rt = (e >> 12) & 1;
      const int R = rt*32 + (lane & 31);
      const int K = ks*16 + (lane >> 5)*8 + j;
      float v = 0.0f;
      if (R < RUSE && K < RUSE && (R/17) == (K/17))
        v = Ash[(R%17)*17 + (K%17)];
      const unsigned short hi = f2bf(v);
      pret_a[e] = hl ? f2bf(v - bf2f(hi)) : hi;
    }
  }
}

__global__ __launch_bounds__(512, 6)
void gcn_main(const float* __restrict__ x, const float* __restrict__ b_in,
              const float* __restrict__ bs, const float* __restrict__ b_out,
              const unsigned short* __restrict__ pret_a,
              const unsigned short* __restrict__ pret_in,
              const unsigned short* __restrict__ pret_out,
              const unsigned short* __restrict__ pret_b,
              float* __restrict__ out)
{
  __shared__ unsigned short h[RPAD*HID];            // 32 KB, single buffer
  __shared__ unsigned short al[8192];               // 16 KB Ahat_bd frags
  __shared__ unsigned short xt[RPAD*32];            // 4 KB x-tile

  const int tid  = threadIdx.x;
  const int lane = tid & 63;
  const int wid  = tid >> 6;
  const int kh   = lane >> 5;
  const int l31  = lane & 31;
  const int c    = wid*32 + l31;
  const int wg   = blockIdx.x;

  const char* h_b = (const char*)h;

  // ---- B prefetch: single bf16 W frags straight from global (L2-resident) ----
  const unsigned short* pb = pret_b + kh*2048 + c*8;
  short8 BA, BB;                                    // W frag for one k-step
  auto loadB = [&](int t, short8& d){
    d = *(const short8*)(pb + t*4096);
  };
  loadB(0, BA);
  const short8 BI = *(const short8*)(pret_in + kh*2048 + c*8);

  // ---- stage x tile + Ahat_bd frags -> LDS ----
  {
    const int r = tid >> 3, k4 = (tid & 7) << 2;
    short4v v = (short4v)0;
    if (r < RUSE && k4 == 0){
      const int s = r/17, j = r - s*17;
      const float* xb = x + (size_t)(wg*SPW + s)*51 + j*3;
      v.x = (short)f2bf(xb[0]); v.y = (short)f2bf(xb[1]); v.z = (short)f2bf(xb[2]);
    }
    *(short4v*)(xt + r*32 + k4) = v;
    short8* al8 = (short8*)al;
    const short8* pa8 = (const short8*)pret_a;
    al8[tid]       = pa8[tid];
    al8[tid + 512] = pa8[tid + 512];
  }
  __syncthreads();

  // ---- input projection as MFMA: h0 = x @ w_in + b_in -> h (bf16) ----
  float16 acc[2];
  {
    const float bc = b_in[c];
#pragma unroll
    for (int rt=0; rt<2; ++rt)
#pragma unroll
    for (int q=0; q<16; ++q) acc[rt][q] = bc;
#pragma unroll
    for (int rt=0; rt<2; ++rt){
      const short8 Ax = *(const short8*)(xt + (rt*32 + l31)*32 + kh*8);
      acc[rt] = __builtin_amdgcn_mfma_f32_32x32x16_bf16(Ax, BI, acc[rt], 0,0,0);
    }
#pragma unroll
    for (int rt=0; rt<2; ++rt)
#pragma unroll
    for (int q=0; q<16; ++q){
      const int r  = rt*32 + (q&3) + 8*(q>>2) + 4*kh;
      const int hb = (r << 9) + ((2*c) ^ ((r & 31) << 4));
      h[hb >> 1] = f2bf(acc[rt][q]);
    }
  }
  __syncthreads();

  // ---- layers: GEMM reads h -> barrier -> in-place pointwise -> barrier ----
#pragma unroll 1
  for (int layer=0; layer<NLAY; ++layer){
#pragma unroll
    for (int rt=0; rt<2; ++rt)
#pragma unroll
    for (int q=0; q<16; ++q) acc[rt][q] = 0.0f;

    auto step = [&](int ksl, const short8 B){
      short8 Ah[2];
#pragma unroll
      for (int rt=0; rt<2; ++rt){
        const int r   = rt*32 + l31;
        const int off = (r << 9) + ((ksl*32 + kh*16) ^ ((r & 31) << 4));
        Ah[rt] = *(const short8*)(h_b + off);
      }
#pragma unroll
      for (int rt=0; rt<2; ++rt)
        acc[rt] = __builtin_amdgcn_mfma_f32_32x32x16_bf16(Ah[rt], B, acc[rt], 0,0,0);
    };

    const int t0 = layer*16;
#pragma unroll
    for (int ks=0; ks<16; ks+=2){
      loadB(t0 + ks + 1, BB);
      step(ks, BA);
      loadB(min(t0 + ks + 2, 63), BA);
      step(ks + 1, BB);
    }

    // ---- repack S (acc, C-layout) into mix B-frags Bs[ks] (k = 16ks+8kh+j) ----
    // acc is fully dead after this block; it is then reused as the mix accumulator.
    short8 Bs[4];
#pragma unroll
    for (int ks=0; ks<4; ++ks){
      const int rt = ks >> 1;
      const int lq = ((2*ks) & 3) << 2;        // slots of rows 16ks+i (h0) / +4+i (h1)
      const int hq = ((2*ks + 1) & 3) << 2;    // slots of rows 16ks+8+i (h0) / +12+i (h1)
#pragma unroll
      for (int i=0; i<4; ++i){
        const float lo_v = acc[rt][lq | i];
        const float hi_v = acc[rt][hq | i];
        const float send = kh ? lo_v : hi_v;   // what partner half needs
        const float own  = kh ? hi_v : lo_v;   // what I keep
        const float recv = __shfl_xor(send, 32, 64);
        const float f_i  = kh ? recv : own;    // frag element j=i
        const float f_i4 = kh ? own  : recv;   // frag element j=4+i
        Bs[ks][i]     = (short)f2bf(f_i);
        Bs[ks][4 + i] = (short)f2bf(f_i4);
      }
    }

    // ---- mix MFMA into REUSED acc: acc = Ahat_bd(hi+lo) @ S, fenced ----
#pragma unroll
    for (int rt2=0; rt2<2; ++rt2)
#pragma unroll
    for (int q=0; q<16; ++q) acc[rt2][q] = 0.0f;
    __builtin_amdgcn_sched_barrier(0);
    const short8* al8 = (const short8*)al;
#pragma unroll
    for (int ks=0; ks<4; ++ks){
      {
        const short8 Ahi = al8[(ks*2 + 0)*64 + lane];
        const short8 Alo = al8[(ks*2 + 1)*64 + lane];
        acc[0] = __builtin_amdgcn_mfma_f32_32x32x16_bf16(Ahi, Bs[ks], acc[0], 0,0,0);
        acc[0] = __builtin_amdgcn_mfma_f32_32x32x16_bf16(Alo, Bs[ks], acc[0], 0,0,0);
      }
      __builtin_amdgcn_sched_barrier(0);
      {
        const short8 Ahi = al8[((4 + ks)*2 + 0)*64 + lane];
        const short8 Alo = al8[((4 + ks)*2 + 1)*64 + lane];
        acc[1] = __builtin_amdgcn_mfma_f32_32x32x16_bf16(Ahi, Bs[ks], acc[1], 0,0,0);
        acc[1] = __builtin_amdgcn_mfma_f32_32x32x16_bf16(Alo, Bs[ks], acc[1], 0,0,0);
      }
      __builtin_amdgcn_sched_barrier(0);
    }

    __syncthreads();   // all GEMM h-reads done before in-place writes

    // ---- pointwise in-place: h = relu(acc + bias) + h (owner slots only) ----
    {
      const float bsv = bs[layer*256 + c];
#pragma unroll
      for (int rt2=0; rt2<2; ++rt2)
#pragma unroll
      for (int q=0; q<16; ++q){
        const int r   = rt2*32 + (q&3) + 8*(q>>2) + 4*kh;
        const int off = (r << 9) + ((2*c) ^ ((r & 31) << 4));
        const float o = fmaxf(acc[rt2][q] + bsv, 0.0f) + bf2f(h[off >> 1]);
        h[off >> 1] = f2bf(o);
      }
    }
    __syncthreads();
  }

  // ---- output projection as MFMA on wave 0: y = h @ w_out + b_out ----
  if (wid == 0){
    const float bo = (l31 < 3) ? b_out[l31] : 0.0f;
    float16 y[2];
#pragma unroll
    for (int rt=0; rt<2; ++rt)
#pragma unroll
    for (int q=0; q<16; ++q) y[rt][q] = bo;

    const unsigned short* po = pret_out + kh*256 + l31*8;
#pragma unroll
    for (int ks=0; ks<16; ++ks){
      const short8 Bh = *(const short8*)(po + ks*512);
      const short8 Bl = *(const short8*)(po + 8192 + ks*512);
      short8 Ah[2];
#pragma unroll
      for (int rt=0; rt<2; ++rt){
        const int r   = rt*32 + l31;
        const int off = (r << 9) + ((ks*32 + kh*16) ^ ((r & 31) << 4));
        Ah[rt] = *(const short8*)(h_b + off);
      }
#pragma unroll
      for (int rt=0; rt<2; ++rt){
        y[rt] = __builtin_amdgcn_mfma_f32_32x32x16_bf16(Ah[rt], Bh, y[rt], 0,0,0);
        y[rt] = __builtin_amdgcn_mfma_f32_32x32x16_bf16(Ah[rt], Bl, y[rt], 0,0,0);
      }
    }
#pragma unroll
    for (int rt=0; rt<2; ++rt)
#pragma unroll
    for (int q=0; q<16; ++q){
      const int r0 = rt*32 + (q&3) + 8*(q>>2);
      const int r  = r0 + 4*kh;
      if (r < RUSE && l31 < 3){
        const int s = r/17, jj = r - s*17;
        out[((size_t)(wg*SPW + s)*17 + jj)*3 + l31] = y[rt][q];
      }
    }
  }
}

extern "C" void kernel_launch(void* const* d_in, const int* in_sizes, int n_in,
                              void* d_out, int out_size, void* d_ws, size_t ws_size,
                              hipStream_t stream)
{
  const float* x     = (const float*)d_in[0];
  const float* adj   = (const float*)d_in[1];
  const float* w_in  = (const float*)d_in[2];
  const float* b_in  = (const float*)d_in[3];
  const float* Ws    = (const float*)d_in[4];
  const float* bs    = (const float*)d_in[5];
  const float* w_out = (const float*)d_in[6];
  const float* b_out = (const float*)d_in[7];
  float* out = (float*)d_out;

  unsigned short* pret_a   = (unsigned short*)d_ws;                      // 16 KB
  unsigned short* pret_in  = (unsigned short*)((char*)d_ws + 16384);    // 8 KB
  unsigned short* pret_out = (unsigned short*)((char*)d_ws + 24576);    // 32 KB
  unsigned short* pret_b   = (unsigned short*)((char*)d_ws + 65536);    // 512 KB

  hipLaunchKernelGGL(gcn_prep, dim3(1025), dim3(256), 0, stream,
                     adj, Ws, w_in, w_out, pret_a, pret_in, pret_out, pret_b);
  hipLaunchKernelGGL(gcn_main, dim3(NWG), dim3(512), 0, stream,
                     x, b_in, bs, b_out, pret_a, pret_in, pret_out, pret_b, out);
}

// Round 13
// 368.485 us; speedup vs baseline: 1.3746x; 1.3746x over previous
//
#include <hip/hip_runtime.h>
#include <hip/hip_bf16.h>
#include <stdint.h>

// GCN pose: fused per-sample chain. 64*243=15552 samples, 17 joints, hidden 256, 4 layers.
// Round 13: r11 base (single-pass bf16 W GEMM, exact hi/lo Ahat MFMA mix, h double-buffer,
// 1 barrier/layer, fenced mix liveness, 512thr/4waves-per-SIMD) + 4-deep B prefetch ring
// (Br[4], load-after-use): B L2 latency hidden across 3 steps + the mix phase at layer
// boundaries. r12 lesson: <=85 VGPR infeasible (spilled 604 MB) — stay at the 128 cap.

#define J17   17
#define HID   256
#define NLAY  4
#define NSAMP 15552
#define SPW   3
#define RUSE  51         // SPW*17 used rows
#define RPAD  64         // padded rows (2 row-tiles of 32)
#define NWG   5184       // NSAMP/SPW exactly

typedef __attribute__((ext_vector_type(4)))  short  short4v;
typedef __attribute__((ext_vector_type(8)))  short  short8;
typedef __attribute__((ext_vector_type(16))) float  float16;

__device__ __forceinline__ unsigned short f2bf(float f){
  return __bfloat16_as_ushort(__float2bfloat16(f));   // v_cvt, RNE
}
__device__ __forceinline__ float bf2f(unsigned short b){
  return __builtin_bit_cast(float, ((unsigned)b) << 16);
}

// ---------------- prep ----------------
// pret_b (512 KB): [t(64)][kh(2)][c(256)][j(8)], value = bf16(W[t>>4][k][c]),
//                k = (t&15)*16 + kh*8 + j
// pret_in (8 KB): [kh(2)][c(256)][j(8)] = bf16(w_in[k][c]), k = kh*8+j (<3 else 0)
// pret_out (32 KB): [hl(2)][ks(16)][kh(2)][col(32)][j(8)] = split(w_out[k][col], hl)
// pret_a (16 KB): [rt(2)][ks(4)][hl(2)][lane(64)][j(8)] = split(Ahat_bd[R][K], hl),
//                R = rt*32 + (lane&31), K = ks*16 + (lane>>5)*8 + j
__global__ __launch_bounds__(256)
void gcn_prep(const float* __restrict__ adj, const float* __restrict__ Ws,
              const float* __restrict__ w_in, const float* __restrict__ w_out,
              unsigned short* __restrict__ pret_a, unsigned short* __restrict__ pret_in,
              unsigned short* __restrict__ pret_out, unsigned short* __restrict__ pret_b)
{
  if (blockIdx.x < 1024){
    const int e  = blockIdx.x*256 + threadIdx.x;
    const int j  = e & 7, cc = (e >> 3) & 255, khh = (e >> 11) & 1, t = e >> 12;
    const int k  = (t & 15)*16 + khh*8 + j;
    pret_b[(t*2 + khh)*2048 + cc*8 + j] = f2bf(Ws[(t >> 4)*65536 + k*256 + cc]);
  } else {
    const int tid = threadIdx.x;
    __shared__ float Ash[289];
    for (int t = tid; t < 289; t += 256){
      const int j = t/17, k2 = t%17;
      float dj = 1e-5f, dk = 1e-5f;
      for (int m=0;m<17;++m){ dj += adj[j*17+m]; dk += adj[k2*17+m]; }
      Ash[t] = adj[t] / (sqrtf(dj)*sqrtf(dk));
    }
    __syncthreads();
    for (int e = tid; e < 4096; e += 256){
      const int j = e & 7, cc = (e >> 3) & 255, khh = e >> 11;
      const int k = khh*8 + j;
      pret_in[e] = (k < 3) ? f2bf(w_in[k*256 + cc]) : (unsigned short)0;
    }
    for (int e = tid; e < 8192; e += 256){
      const int j = e & 7, col = (e >> 3) & 31, khh = (e >> 8) & 1, ks = e >> 9;
      const int k = ks*16 + khh*8 + j;
      const float w = (col < 3) ? w_out[k*3 + col] : 0.0f;
      const unsigned short hi = f2bf(w);
      const int idx = ((ks*2 + khh)*32 + col)*8 + j;
      pret_out[idx]        = hi;
      pret_out[idx + 8192] = f2bf(w - bf2f(hi));
    }
    // Ahat_bd fragments (hi/lo split keeps the graph mix exact)
    for (int e = tid; e < 8192; e += 256){
      const int j = e & 7, lane = (e >> 3) & 63, hl = (e >> 9) & 1;
      const int ks = (e >> 10) & 3, rt = (e >> 12) & 1;
      const int R = rt*32 + (lane & 31);
      const int K = ks*16 + (lane >> 5)*8 + j;
      float v = 0.0f;
      if (R < RUSE && K < RUSE && (R/17) == (K/17))
        v = Ash[(R%17)*17 + (K%17)];
      const unsigned short hi = f2bf(v);
      pret_a[e] = hl ? f2bf(v - bf2f(hi)) : hi;
    }
  }
}

__global__ __launch_bounds__(512, 4)
void gcn_main(const float* __restrict__ x, const float* __restrict__ b_in,
              const float* __restrict__ bs, const float* __restrict__ b_out,
              const unsigned short* __restrict__ pret_a,
              const unsigned short* __restrict__ pret_in,
              const unsigned short* __restrict__ pret_out,
              const unsigned short* __restrict__ pret_b,
              float* __restrict__ out)
{
  __shared__ unsigned short h[2*RPAD*HID];          // 64 KB: two 32 KB buffers
  __shared__ unsigned short al[8192];               // 16 KB Ahat_bd frags
  unsigned short* xt = h + RPAD*HID;                // x-tile aliases buf1 (dead by mix0)

  const int tid  = threadIdx.x;
  const int lane = tid & 63;
  const int wid  = tid >> 6;
  const int kh   = lane >> 5;
  const int l31  = lane & 31;
  const int c    = wid*32 + l31;
  const int wg   = blockIdx.x;

  const char* h_b = (const char*)h;

  // ---- B prefetch ring (depth 4): bf16 W frags straight from global (L2) ----
  const unsigned short* pb = pret_b + kh*2048 + c*8;
  short8 Br[4];
  auto loadB = [&](int t, short8& d){
    d = *(const short8*)(pb + t*4096);
  };
#pragma unroll
  for (int i=0;i<4;++i) loadB(i, Br[i]);
  const short8 BI = *(const short8*)(pret_in + kh*2048 + c*8);

  // ---- stage x tile (in buf1 alias) + Ahat_bd frags -> LDS ----
  {
    const int r = tid >> 3, k4 = (tid & 7) << 2;
    short4v v = (short4v)0;
    if (r < RUSE && k4 == 0){
      const int s = r/17, j = r - s*17;
      const float* xb = x + (size_t)(wg*SPW + s)*51 + j*3;
      v.x = (short)f2bf(xb[0]); v.y = (short)f2bf(xb[1]); v.z = (short)f2bf(xb[2]);
    }
    *(short4v*)(xt + r*32 + k4) = v;
    short8* al8 = (short8*)al;
    const short8* pa8 = (const short8*)pret_a;
    al8[tid]       = pa8[tid];
    al8[tid + 512] = pa8[tid + 512];
  }
  __syncthreads();

  // ---- input projection as MFMA: h0 = x @ w_in + b_in -> buf0 (bf16) ----
  float16 acc[2];
  {
    const float bc = b_in[c];
#pragma unroll
    for (int rt=0; rt<2; ++rt)
#pragma unroll
    for (int q=0; q<16; ++q) acc[rt][q] = bc;
#pragma unroll
    for (int rt=0; rt<2; ++rt){
      const short8 Ax = *(const short8*)(xt + (rt*32 + l31)*32 + kh*8);
      acc[rt] = __builtin_amdgcn_mfma_f32_32x32x16_bf16(Ax, BI, acc[rt], 0,0,0);
    }
#pragma unroll
    for (int rt=0; rt<2; ++rt)
#pragma unroll
    for (int q=0; q<16; ++q){
      const int r  = rt*32 + (q&3) + 8*(q>>2) + 4*kh;
      const int hb = (r << 9) + ((2*c) ^ ((r & 31) << 4));
      h[hb >> 1] = f2bf(acc[rt][q]);
    }
  }
  __syncthreads();

  // ---- layers: read buf[l&1], write buf[(l+1)&1]; ONE barrier per layer ----
#pragma unroll 1
  for (int layer=0; layer<NLAY; ++layer){
    const char* hr = h_b + (size_t)((layer & 1) * (RPAD*HID*2));
    const unsigned short* hru = (const unsigned short*)hr;
#pragma unroll
    for (int rt=0; rt<2; ++rt)
#pragma unroll
    for (int q=0; q<16; ++q) acc[rt][q] = 0.0f;

    auto step = [&](int ksl, const short8 B){
      short8 Ah[2];
#pragma unroll
      for (int rt=0; rt<2; ++rt){
        const int r   = rt*32 + l31;
        const int off = (r << 9) + ((ksl*32 + kh*16) ^ ((r & 31) << 4));
        Ah[rt] = *(const short8*)(hr + off);
      }
#pragma unroll
      for (int rt=0; rt<2; ++rt)
        acc[rt] = __builtin_amdgcn_mfma_f32_32x32x16_bf16(Ah[rt], B, acc[rt], 0,0,0);
    };

#pragma unroll
    for (int ks=0; ks<16; ++ks){
      step(ks, Br[ks & 3]);
      loadB(min(layer*16 + ks + 4, 63), Br[ks & 3]);   // refill slot; lands 3 steps
    }                                                   // (+ mix phase) later

    // ---- repack S (acc, C-layout) into mix B-frags Bs[ks] (k = 16ks+8kh+j) ----
    // acc is fully dead after this block (16 bf16x8 regs replace 32 f32).
    short8 Bs[4];
#pragma unroll
    for (int ks=0; ks<4; ++ks){
      const int rt = ks >> 1;
      const int lq = ((2*ks) & 3) << 2;        // slots of rows 16ks+i (h0) / +4+i (h1)
      const int hq = ((2*ks + 1) & 3) << 2;    // slots of rows 16ks+8+i (h0) / +12+i (h1)
#pragma unroll
      for (int i=0; i<4; ++i){
        const float lo_v = acc[rt][lq | i];
        const float hi_v = acc[rt][hq | i];
        const float send = kh ? lo_v : hi_v;   // what partner half needs
        const float own  = kh ? hi_v : lo_v;   // what I keep
        const float recv = __shfl_xor(send, 32, 64);
        const float f_i  = kh ? recv : own;    // frag element j=i
        const float f_i4 = kh ? own  : recv;   // frag element j=4+i
        Bs[ks][i]     = (short)f2bf(f_i);
        Bs[ks][4 + i] = (short)f2bf(f_i4);
      }
    }

    // ---- mix MFMA: m2 = Ahat_bd(hi+lo) @ S, fenced to cap liveness ----
    float16 m2[2];
#pragma unroll
    for (int rt2=0; rt2<2; ++rt2)
#pragma unroll
    for (int q=0; q<16; ++q) m2[rt2][q] = 0.0f;
    __builtin_amdgcn_sched_barrier(0);
    const short8* al8 = (const short8*)al;
#pragma unroll
    for (int ks=0; ks<4; ++ks){
      {
        const short8 Ahi = al8[(ks*2 + 0)*64 + lane];
        const short8 Alo = al8[(ks*2 + 1)*64 + lane];
        m2[0] = __builtin_amdgcn_mfma_f32_32x32x16_bf16(Ahi, Bs[ks], m2[0], 0,0,0);
        m2[0] = __builtin_amdgcn_mfma_f32_32x32x16_bf16(Alo, Bs[ks], m2[0], 0,0,0);
      }
      __builtin_amdgcn_sched_barrier(0);
      {
        const short8 Ahi = al8[((4 + ks)*2 + 0)*64 + lane];
        const short8 Alo = al8[((4 + ks)*2 + 1)*64 + lane];
        m2[1] = __builtin_amdgcn_mfma_f32_32x32x16_bf16(Ahi, Bs[ks], m2[1], 0,0,0);
        m2[1] = __builtin_amdgcn_mfma_f32_32x32x16_bf16(Alo, Bs[ks], m2[1], 0,0,0);
      }
      __builtin_amdgcn_sched_barrier(0);
    }

    // ---- pointwise: h' = relu(m2 + bias) + h  (all slots, pad rows stay finite) ----
    {
      const float bsv = bs[layer*256 + c];
      unsigned short* hw = h + (((layer & 1) ^ 1) * RPAD*HID);
#pragma unroll
      for (int rt2=0; rt2<2; ++rt2)
#pragma unroll
      for (int q=0; q<16; ++q){
        const int r   = rt2*32 + (q&3) + 8*(q>>2) + 4*kh;
        const int off = (r << 9) + ((2*c) ^ ((r & 31) << 4));
        const float o = fmaxf(m2[rt2][q] + bsv, 0.0f) + bf2f(hru[off >> 1]);
        hw[off >> 1] = f2bf(o);
      }
    }
    __syncthreads();
  }

  // ---- output projection as MFMA on wave 0: y = h @ w_out + b_out ----
  if (wid == 0){
    const float bo = (l31 < 3) ? b_out[l31] : 0.0f;
    float16 y[2];
#pragma unroll
    for (int rt=0; rt<2; ++rt)
#pragma unroll
    for (int q=0; q<16; ++q) y[rt][q] = bo;

    const unsigned short* po = pret_out + kh*256 + l31*8;
#pragma unroll
    for (int ks=0; ks<16; ++ks){
      const short8 Bh = *(const short8*)(po + ks*512);
      const short8 Bl = *(const short8*)(po + 8192 + ks*512);
      short8 Ah[2];
#pragma unroll
      for (int rt=0; rt<2; ++rt){
        const int r   = rt*32 + l31;
        const int off = (r << 9) + ((ks*32 + kh*16) ^ ((r & 31) << 4));
        Ah[rt] = *(const short8*)(h_b + off);          // final h is buf0
      }
#pragma unroll
      for (int rt=0; rt<2; ++rt){
        y[rt] = __builtin_amdgcn_mfma_f32_32x32x16_bf16(Ah[rt], Bh, y[rt], 0,0,0);
        y[rt] = __builtin_amdgcn_mfma_f32_32x32x16_bf16(Ah[rt], Bl, y[rt], 0,0,0);
      }
    }
#pragma unroll
    for (int rt=0; rt<2; ++rt)
#pragma unroll
    for (int q=0; q<16; ++q){
      const int r0 = rt*32 + (q&3) + 8*(q>>2);
      const int r  = r0 + 4*kh;
      if (r < RUSE && l31 < 3){
        const int s = r/17, jj = r - s*17;
        out[((size_t)(wg*SPW + s)*17 + jj)*3 + l31] = y[rt][q];
      }
    }
  }
}

extern "C" void kernel_launch(void* const* d_in, const int* in_sizes, int n_in,
                              void* d_out, int out_size, void* d_ws, size_t ws_size,
                              hipStream_t stream)
{
  const float* x     = (const float*)d_in[0];
  const float* adj   = (const float*)d_in[1];
  const float* w_in  = (const float*)d_in[2];
  const float* b_in  = (const float*)d_in[3];
  const float* Ws    = (const float*)d_in[4];
  const float* bs    = (const float*)d_in[5];
  const float* w_out = (const float*)d_in[6];
  const float* b_out = (const float*)d_in[7];
  float* out = (float*)d_out;

  unsigned short* pret_a   = (unsigned short*)d_ws;                      // 16 KB
  unsigned short* pret_in  = (unsigned short*)((char*)d_ws + 16384);    // 8 KB
  unsigned short* pret_out = (unsigned short*)((char*)d_ws + 24576);    // 32 KB
  unsigned short* pret_b   = (unsigned short*)((char*)d_ws + 65536);    // 512 KB

  hipLaunchKernelGGL(gcn_prep, dim3(1025), dim3(256), 0, stream,
                     adj, Ws, w_in, w_out, pret_a, pret_in, pret_out, pret_b);
  hipLaunchKernelGGL(gcn_main, dim3(NWG), dim3(512), 0, stream,
                     x, b_in, bs, b_out, pret_a, pret_in, pret_out, pret_b, out);
}

// Round 14
// 349.519 us; speedup vs baseline: 1.4492x; 1.0543x over previous
//
#include <hip/hip_runtime.h>
#include <hip/hip_bf16.h>
#include <stdint.h>

// GCN pose: fused per-sample chain. 64*243=15552 samples, 17 joints, hidden 256, 4 layers.
// Round 14: r11 base (single-pass bf16 W GEMM, exact hi/lo Ahat MFMA mix, h double-buffer,
// 1 barrier/layer, 512thr/4waves-per-SIMD) + software-pipelined mix: named F/G frag-pair
// rotation, prefetch next block's al frags before current block's MFMAs, fence per block.
// Caps in-flight frags at 2 pairs (32 regs) — same liveness as r11's 8 fences but the
// ds_read latency now hides under MFMAs. r12/r13 lesson: any always-live +16 regs spills;
// this adds live regs only inside the mix phase where acc is dead.

#define J17   17
#define HID   256
#define NLAY  4
#define NSAMP 15552
#define SPW   3
#define RUSE  51         // SPW*17 used rows
#define RPAD  64         // padded rows (2 row-tiles of 32)
#define NWG   5184       // NSAMP/SPW exactly

typedef __attribute__((ext_vector_type(4)))  short  short4v;
typedef __attribute__((ext_vector_type(8)))  short  short8;
typedef __attribute__((ext_vector_type(16))) float  float16;

__device__ __forceinline__ unsigned short f2bf(float f){
  return __bfloat16_as_ushort(__float2bfloat16(f));   // v_cvt, RNE
}
__device__ __forceinline__ float bf2f(unsigned short b){
  return __builtin_bit_cast(float, ((unsigned)b) << 16);
}

// ---------------- prep ----------------
// pret_b (512 KB): [t(64)][kh(2)][c(256)][j(8)], value = bf16(W[t>>4][k][c]),
//                k = (t&15)*16 + kh*8 + j
// pret_in (8 KB): [kh(2)][c(256)][j(8)] = bf16(w_in[k][c]), k = kh*8+j (<3 else 0)
// pret_out (32 KB): [hl(2)][ks(16)][kh(2)][col(32)][j(8)] = split(w_out[k][col], hl)
// pret_a (16 KB): [rt(2)][ks(4)][hl(2)][lane(64)][j(8)] = split(Ahat_bd[R][K], hl),
//                R = rt*32 + (lane&31), K = ks*16 + (lane>>5)*8 + j
__global__ __launch_bounds__(256)
void gcn_prep(const float* __restrict__ adj, const float* __restrict__ Ws,
              const float* __restrict__ w_in, const float* __restrict__ w_out,
              unsigned short* __restrict__ pret_a, unsigned short* __restrict__ pret_in,
              unsigned short* __restrict__ pret_out, unsigned short* __restrict__ pret_b)
{
  if (blockIdx.x < 1024){
    const int e  = blockIdx.x*256 + threadIdx.x;
    const int j  = e & 7, cc = (e >> 3) & 255, khh = (e >> 11) & 1, t = e >> 12;
    const int k  = (t & 15)*16 + khh*8 + j;
    pret_b[(t*2 + khh)*2048 + cc*8 + j] = f2bf(Ws[(t >> 4)*65536 + k*256 + cc]);
  } else {
    const int tid = threadIdx.x;
    __shared__ float Ash[289];
    for (int t = tid; t < 289; t += 256){
      const int j = t/17, k2 = t%17;
      float dj = 1e-5f, dk = 1e-5f;
      for (int m=0;m<17;++m){ dj += adj[j*17+m]; dk += adj[k2*17+m]; }
      Ash[t] = adj[t] / (sqrtf(dj)*sqrtf(dk));
    }
    __syncthreads();
    for (int e = tid; e < 4096; e += 256){
      const int j = e & 7, cc = (e >> 3) & 255, khh = e >> 11;
      const int k = khh*8 + j;
      pret_in[e] = (k < 3) ? f2bf(w_in[k*256 + cc]) : (unsigned short)0;
    }
    for (int e = tid; e < 8192; e += 256){
      const int j = e & 7, col = (e >> 3) & 31, khh = (e >> 8) & 1, ks = e >> 9;
      const int k = ks*16 + khh*8 + j;
      const float w = (col < 3) ? w_out[k*3 + col] : 0.0f;
      const unsigned short hi = f2bf(w);
      const int idx = ((ks*2 + khh)*32 + col)*8 + j;
      pret_out[idx]        = hi;
      pret_out[idx + 8192] = f2bf(w - bf2f(hi));
    }
    // Ahat_bd fragments (hi/lo split keeps the graph mix exact)
    for (int e = tid; e < 8192; e += 256){
      const int j = e & 7, lane = (e >> 3) & 63, hl = (e >> 9) & 1;
      const int ks = (e >> 10) & 3, rt = (e >> 12) & 1;
      const int R = rt*32 + (lane & 31);
      const int K = ks*16 + (lane >> 5)*8 + j;
      float v = 0.0f;
      if (R < RUSE && K < RUSE && (R/17) == (K/17))
        v = Ash[(R%17)*17 + (K%17)];
      const unsigned short hi = f2bf(v);
      pret_a[e] = hl ? f2bf(v - bf2f(hi)) : hi;
    }
  }
}

__global__ __launch_bounds__(512, 4)
void gcn_main(const float* __restrict__ x, const float* __restrict__ b_in,
              const float* __restrict__ bs, const float* __restrict__ b_out,
              const unsigned short* __restrict__ pret_a,
              const unsigned short* __restrict__ pret_in,
              const unsigned short* __restrict__ pret_out,
              const unsigned short* __restrict__ pret_b,
              float* __restrict__ out)
{
  __shared__ unsigned short h[2*RPAD*HID];          // 64 KB: two 32 KB buffers
  __shared__ unsigned short al[8192];               // 16 KB Ahat_bd frags
  unsigned short* xt = h + RPAD*HID;                // x-tile aliases buf1 (dead by mix0)

  const int tid  = threadIdx.x;
  const int lane = tid & 63;
  const int wid  = tid >> 6;
  const int kh   = lane >> 5;
  const int l31  = lane & 31;
  const int c    = wid*32 + l31;
  const int wg   = blockIdx.x;

  const char* h_b = (const char*)h;

  // ---- B prefetch: single bf16 W frags straight from global (L2-resident) ----
  const unsigned short* pb = pret_b + kh*2048 + c*8;
  short8 BA, BB;                                    // W frag for one k-step
  auto loadB = [&](int t, short8& d){
    d = *(const short8*)(pb + t*4096);
  };
  loadB(0, BA);
  const short8 BI = *(const short8*)(pret_in + kh*2048 + c*8);

  // ---- stage x tile (in buf1 alias) + Ahat_bd frags -> LDS ----
  {
    const int r = tid >> 3, k4 = (tid & 7) << 2;
    short4v v = (short4v)0;
    if (r < RUSE && k4 == 0){
      const int s = r/17, j = r - s*17;
      const float* xb = x + (size_t)(wg*SPW + s)*51 + j*3;
      v.x = (short)f2bf(xb[0]); v.y = (short)f2bf(xb[1]); v.z = (short)f2bf(xb[2]);
    }
    *(short4v*)(xt + r*32 + k4) = v;
    short8* al8s = (short8*)al;
    const short8* pa8 = (const short8*)pret_a;
    al8s[tid]       = pa8[tid];
    al8s[tid + 512] = pa8[tid + 512];
  }
  __syncthreads();

  // ---- input projection as MFMA: h0 = x @ w_in + b_in -> buf0 (bf16) ----
  float16 acc[2];
  {
    const float bc = b_in[c];
#pragma unroll
    for (int rt=0; rt<2; ++rt)
#pragma unroll
    for (int q=0; q<16; ++q) acc[rt][q] = bc;
#pragma unroll
    for (int rt=0; rt<2; ++rt){
      const short8 Ax = *(const short8*)(xt + (rt*32 + l31)*32 + kh*8);
      acc[rt] = __builtin_amdgcn_mfma_f32_32x32x16_bf16(Ax, BI, acc[rt], 0,0,0);
    }
#pragma unroll
    for (int rt=0; rt<2; ++rt)
#pragma unroll
    for (int q=0; q<16; ++q){
      const int r  = rt*32 + (q&3) + 8*(q>>2) + 4*kh;
      const int hb = (r << 9) + ((2*c) ^ ((r & 31) << 4));
      h[hb >> 1] = f2bf(acc[rt][q]);
    }
  }
  __syncthreads();

  // ---- layers: read buf[l&1], write buf[(l+1)&1]; ONE barrier per layer ----
#pragma unroll 1
  for (int layer=0; layer<NLAY; ++layer){
    const char* hr = h_b + (size_t)((layer & 1) * (RPAD*HID*2));
    const unsigned short* hru = (const unsigned short*)hr;
#pragma unroll
    for (int rt=0; rt<2; ++rt)
#pragma unroll
    for (int q=0; q<16; ++q) acc[rt][q] = 0.0f;

    auto step = [&](int ksl, const short8 B){
      short8 Ah[2];
#pragma unroll
      for (int rt=0; rt<2; ++rt){
        const int r   = rt*32 + l31;
        const int off = (r << 9) + ((ksl*32 + kh*16) ^ ((r & 31) << 4));
        Ah[rt] = *(const short8*)(hr + off);
      }
#pragma unroll
      for (int rt=0; rt<2; ++rt)
        acc[rt] = __builtin_amdgcn_mfma_f32_32x32x16_bf16(Ah[rt], B, acc[rt], 0,0,0);
    };

    const int t0 = layer*16;
#pragma unroll
    for (int ks=0; ks<16; ks+=2){
      loadB(t0 + ks + 1, BB);
      step(ks, BA);
      loadB(min(t0 + ks + 2, 63), BA);
      step(ks + 1, BB);
    }

    // ---- repack S (acc, C-layout) into mix B-frags Bs[ks] (k = 16ks+8kh+j) ----
    // acc is fully dead after this block (16 bf16x8 regs replace 32 f32).
    short8 Bs[4];
#pragma unroll
    for (int ks=0; ks<4; ++ks){
      const int rt = ks >> 1;
      const int lq = ((2*ks) & 3) << 2;        // slots of rows 16ks+i (h0) / +4+i (h1)
      const int hq = ((2*ks + 1) & 3) << 2;    // slots of rows 16ks+8+i (h0) / +12+i (h1)
#pragma unroll
      for (int i=0; i<4; ++i){
        const float lo_v = acc[rt][lq | i];
        const float hi_v = acc[rt][hq | i];
        const float send = kh ? lo_v : hi_v;   // what partner half needs
        const float own  = kh ? hi_v : lo_v;   // what I keep
        const float recv = __shfl_xor(send, 32, 64);
        const float f_i  = kh ? recv : own;    // frag element j=i
        const float f_i4 = kh ? own  : recv;   // frag element j=4+i
        Bs[ks][i]     = (short)f2bf(f_i);
        Bs[ks][4 + i] = (short)f2bf(f_i4);
      }
    }

    // ---- mix MFMA: m2 = Ahat_bd(hi+lo) @ S, software-pipelined F/G rotation ----
    // Block b = (ks=b>>1, rt2=b&1); al index (rt2*4+ks). Prefetch block b+1's frags
    // before block b's MFMAs; fence per block caps in-flight frags at 2 pairs.
    float16 m2[2];
#pragma unroll
    for (int rt2=0; rt2<2; ++rt2)
#pragma unroll
    for (int q=0; q<16; ++q) m2[rt2][q] = 0.0f;
    __builtin_amdgcn_sched_barrier(0);
    {
      const short8* al8 = (const short8*)al;
      short8 Fh = al8[0*64 + lane];            // block 0 = (ks0, rt2=0) -> al idx 0
      short8 Fl = al8[1*64 + lane];
      short8 Gh = Fh, Gl = Fl;
#pragma unroll
      for (int b=0; b<8; ++b){
        const int ks  = b >> 1;
        const int rt2 = b & 1;
        if (b < 7){
          const int nks = (b+1) >> 1, nrt2 = (b+1) & 1;
          Gh = al8[((nrt2*4 + nks)*2 + 0)*64 + lane];
          Gl = al8[((nrt2*4 + nks)*2 + 1)*64 + lane];
        }
        m2[rt2] = __builtin_amdgcn_mfma_f32_32x32x16_bf16(Fh, Bs[ks], m2[rt2], 0,0,0);
        m2[rt2] = __builtin_amdgcn_mfma_f32_32x32x16_bf16(Fl, Bs[ks], m2[rt2], 0,0,0);
        __builtin_amdgcn_sched_barrier(0);
        Fh = Gh; Fl = Gl;
      }
    }

    // ---- pointwise: h' = relu(m2 + bias) + h  (all slots, pad rows stay finite) ----
    {
      const float bsv = bs[layer*256 + c];
      unsigned short* hw = h + (((layer & 1) ^ 1) * RPAD*HID);
#pragma unroll
      for (int rt2=0; rt2<2; ++rt2)
#pragma unroll
      for (int q=0; q<16; ++q){
        const int r   = rt2*32 + (q&3) + 8*(q>>2) + 4*kh;
        const int off = (r << 9) + ((2*c) ^ ((r & 31) << 4));
        const float o = fmaxf(m2[rt2][q] + bsv, 0.0f) + bf2f(hru[off >> 1]);
        hw[off >> 1] = f2bf(o);
      }
    }
    __syncthreads();
  }

  // ---- output projection as MFMA on wave 0: y = h @ w_out + b_out ----
  if (wid == 0){
    const float bo = (l31 < 3) ? b_out[l31] : 0.0f;
    float16 y[2];
#pragma unroll
    for (int rt=0; rt<2; ++rt)
#pragma unroll
    for (int q=0; q<16; ++q) y[rt][q] = bo;

    const unsigned short* po = pret_out + kh*256 + l31*8;
#pragma unroll
    for (int ks=0; ks<16; ++ks){
      const short8 Bh = *(const short8*)(po + ks*512);
      const short8 Bl = *(const short8*)(po + 8192 + ks*512);
      short8 Ah[2];
#pragma unroll
      for (int rt=0; rt<2; ++rt){
        const int r   = rt*32 + l31;
        const int off = (r << 9) + ((ks*32 + kh*16) ^ ((r & 31) << 4));
        Ah[rt] = *(const short8*)(h_b + off);          // final h is buf0
      }
#pragma unroll
      for (int rt=0; rt<2; ++rt){
        y[rt] = __builtin_amdgcn_mfma_f32_32x32x16_bf16(Ah[rt], Bh, y[rt], 0,0,0);
        y[rt] = __builtin_amdgcn_mfma_f32_32x32x16_bf16(Ah[rt], Bl, y[rt], 0,0,0);
      }
    }
#pragma unroll
    for (int rt=0; rt<2; ++rt)
#pragma unroll
    for (int q=0; q<16; ++q){
      const int r0 = rt*32 + (q&3) + 8*(q>>2);
      const int r  = r0 + 4*kh;
      if (r < RUSE && l31 < 3){
        const int s = r/17, jj = r - s*17;
        out[((size_t)(wg*SPW + s)*17 + jj)*3 + l31] = y[rt][q];
      }
    }
  }
}

extern "C" void kernel_launch(void* const* d_in, const int* in_sizes, int n_in,
                              void* d_out, int out_size, void* d_ws, size_t ws_size,
                              hipStream_t stream)
{
  const float* x     = (const float*)d_in[0];
  const float* adj   = (const float*)d_in[1];
  const float* w_in  = (const float*)d_in[2];
  const float* b_in  = (const float*)d_in[3];
  const float* Ws    = (const float*)d_in[4];
  const float* bs    = (const float*)d_in[5];
  const float* w_out = (const float*)d_in[6];
  const float* b_out = (const float*)d_in[7];
  float* out = (float*)d_out;

  unsigned short* pret_a   = (unsigned short*)d_ws;                      // 16 KB
  unsigned short* pret_in  = (unsigned short*)((char*)d_ws + 16384);    // 8 KB
  unsigned short* pret_out = (unsigned short*)((char*)d_ws + 24576);    // 32 KB
  unsigned short* pret_b   = (unsigned short*)((char*)d_ws + 65536);    // 512 KB

  hipLaunchKernelGGL(gcn_prep, dim3(1025), dim3(256), 0, stream,
                     adj, Ws, w_in, w_out, pret_a, pret_in, pret_out, pret_b);
  hipLaunchKernelGGL(gcn_main, dim3(NWG), dim3(512), 0, stream,
                     x, b_in, bs, b_out, pret_a, pret_in, pret_out, pret_b, out);
}

// Round 15
// 319.853 us; speedup vs baseline: 1.5836x; 1.0928x over previous
//
#include <hip/hip_runtime.h>
#include <hip/hip_bf16.h>
#include <stdint.h>

// GCN pose: fused per-sample chain. 64*243=15552 samples, 17 joints, hidden 256, 4 layers.
// Round 15: r11 base (single-pass bf16 W GEMM, h double-buffer, 1 barrier/layer, fenced
// mix, 512thr/4waves-per-SIMD) with the Ahat mix ALSO single-pass bf16 (dropped Ahat-lo):
// mix MFMAs 16->8 per layer, al LDS 16->8 KB. Error budget: Ahat-lo's contribution is
// smaller than the S-repack bf16 error already present (measured 0.0156 total).
// r12/r13/r14 lesson: the design sits at the 128-VGPR cliff — remove work, never add regs.

#define J17   17
#define HID   256
#define NLAY  4
#define NSAMP 15552
#define SPW   3
#define RUSE  51         // SPW*17 used rows
#define RPAD  64         // padded rows (2 row-tiles of 32)
#define NWG   5184       // NSAMP/SPW exactly

typedef __attribute__((ext_vector_type(4)))  short  short4v;
typedef __attribute__((ext_vector_type(8)))  short  short8;
typedef __attribute__((ext_vector_type(16))) float  float16;

__device__ __forceinline__ unsigned short f2bf(float f){
  return __bfloat16_as_ushort(__float2bfloat16(f));   // v_cvt, RNE
}
__device__ __forceinline__ float bf2f(unsigned short b){
  return __builtin_bit_cast(float, ((unsigned)b) << 16);
}

// ---------------- prep ----------------
// pret_b (512 KB): [t(64)][kh(2)][c(256)][j(8)], value = bf16(W[t>>4][k][c]),
//                k = (t&15)*16 + kh*8 + j
// pret_in (8 KB): [kh(2)][c(256)][j(8)] = bf16(w_in[k][c]), k = kh*8+j (<3 else 0)
// pret_out (32 KB): [hl(2)][ks(16)][kh(2)][col(32)][j(8)] = split(w_out[k][col], hl)
// pret_a (8 KB): [rt(2)][ks(4)][lane(64)][j(8)] = bf16(Ahat_bd[R][K]),
//                R = rt*32 + (lane&31), K = ks*16 + (lane>>5)*8 + j
__global__ __launch_bounds__(256)
void gcn_prep(const float* __restrict__ adj, const float* __restrict__ Ws,
              const float* __restrict__ w_in, const float* __restrict__ w_out,
              unsigned short* __restrict__ pret_a, unsigned short* __restrict__ pret_in,
              unsigned short* __restrict__ pret_out, unsigned short* __restrict__ pret_b)
{
  if (blockIdx.x < 1024){
    const int e  = blockIdx.x*256 + threadIdx.x;
    const int j  = e & 7, cc = (e >> 3) & 255, khh = (e >> 11) & 1, t = e >> 12;
    const int k  = (t & 15)*16 + khh*8 + j;
    pret_b[(t*2 + khh)*2048 + cc*8 + j] = f2bf(Ws[(t >> 4)*65536 + k*256 + cc]);
  } else {
    const int tid = threadIdx.x;
    __shared__ float Ash[289];
    for (int t = tid; t < 289; t += 256){
      const int j = t/17, k2 = t%17;
      float dj = 1e-5f, dk = 1e-5f;
      for (int m=0;m<17;++m){ dj += adj[j*17+m]; dk += adj[k2*17+m]; }
      Ash[t] = adj[t] / (sqrtf(dj)*sqrtf(dk));
    }
    __syncthreads();
    for (int e = tid; e < 4096; e += 256){
      const int j = e & 7, cc = (e >> 3) & 255, khh = e >> 11;
      const int k = khh*8 + j;
      pret_in[e] = (k < 3) ? f2bf(w_in[k*256 + cc]) : (unsigned short)0;
    }
    for (int e = tid; e < 8192; e += 256){
      const int j = e & 7, col = (e >> 3) & 31, khh = (e >> 8) & 1, ks = e >> 9;
      const int k = ks*16 + khh*8 + j;
      const float w = (col < 3) ? w_out[k*3 + col] : 0.0f;
      const unsigned short hi = f2bf(w);
      const int idx = ((ks*2 + khh)*32 + col)*8 + j;
      pret_out[idx]        = hi;
      pret_out[idx + 8192] = f2bf(w - bf2f(hi));
    }
    // Ahat_bd fragments, single bf16
    for (int e = tid; e < 4096; e += 256){
      const int j = e & 7, lane = (e >> 3) & 63;
      const int ks = (e >> 9) & 3, rt = (e >> 11) & 1;
      const int R = rt*32 + (lane & 31);
      const int K = ks*16 + (lane >> 5)*8 + j;
      float v = 0.0f;
      if (R < RUSE && K < RUSE && (R/17) == (K/17))
        v = Ash[(R%17)*17 + (K%17)];
      pret_a[e] = f2bf(v);
    }
  }
}

__global__ __launch_bounds__(512, 4)
void gcn_main(const float* __restrict__ x, const float* __restrict__ b_in,
              const float* __restrict__ bs, const float* __restrict__ b_out,
              const unsigned short* __restrict__ pret_a,
              const unsigned short* __restrict__ pret_in,
              const unsigned short* __restrict__ pret_out,
              const unsigned short* __restrict__ pret_b,
              float* __restrict__ out)
{
  __shared__ unsigned short h[2*RPAD*HID];          // 64 KB: two 32 KB buffers
  __shared__ unsigned short al[4096];               // 8 KB Ahat_bd frags (bf16)
  unsigned short* xt = h + RPAD*HID;                // x-tile aliases buf1 (dead by mix0)

  const int tid  = threadIdx.x;
  const int lane = tid & 63;
  const int wid  = tid >> 6;
  const int kh   = lane >> 5;
  const int l31  = lane & 31;
  const int c    = wid*32 + l31;
  const int wg   = blockIdx.x;

  const char* h_b = (const char*)h;

  // ---- B prefetch: single bf16 W frags straight from global (L2-resident) ----
  const unsigned short* pb = pret_b + kh*2048 + c*8;
  short8 BA, BB;                                    // W frag for one k-step
  auto loadB = [&](int t, short8& d){
    d = *(const short8*)(pb + t*4096);
  };
  loadB(0, BA);
  const short8 BI = *(const short8*)(pret_in + kh*2048 + c*8);

  // ---- stage x tile (in buf1 alias) + Ahat_bd frags -> LDS ----
  {
    const int r = tid >> 3, k4 = (tid & 7) << 2;
    short4v v = (short4v)0;
    if (r < RUSE && k4 == 0){
      const int s = r/17, j = r - s*17;
      const float* xb = x + (size_t)(wg*SPW + s)*51 + j*3;
      v.x = (short)f2bf(xb[0]); v.y = (short)f2bf(xb[1]); v.z = (short)f2bf(xb[2]);
    }
    *(short4v*)(xt + r*32 + k4) = v;
    short8* al8s = (short8*)al;
    const short8* pa8 = (const short8*)pret_a;
    al8s[tid] = pa8[tid];                           // 512 x 16B = 8 KB
  }
  __syncthreads();

  // ---- input projection as MFMA: h0 = x @ w_in + b_in -> buf0 (bf16) ----
  float16 acc[2];
  {
    const float bc = b_in[c];
#pragma unroll
    for (int rt=0; rt<2; ++rt)
#pragma unroll
    for (int q=0; q<16; ++q) acc[rt][q] = bc;
#pragma unroll
    for (int rt=0; rt<2; ++rt){
      const short8 Ax = *(const short8*)(xt + (rt*32 + l31)*32 + kh*8);
      acc[rt] = __builtin_amdgcn_mfma_f32_32x32x16_bf16(Ax, BI, acc[rt], 0,0,0);
    }
#pragma unroll
    for (int rt=0; rt<2; ++rt)
#pragma unroll
    for (int q=0; q<16; ++q){
      const int r  = rt*32 + (q&3) + 8*(q>>2) + 4*kh;
      const int hb = (r << 9) + ((2*c) ^ ((r & 31) << 4));
      h[hb >> 1] = f2bf(acc[rt][q]);
    }
  }
  __syncthreads();

  // ---- layers: read buf[l&1], write buf[(l+1)&1]; ONE barrier per layer ----
#pragma unroll 1
  for (int layer=0; layer<NLAY; ++layer){
    const char* hr = h_b + (size_t)((layer & 1) * (RPAD*HID*2));
    const unsigned short* hru = (const unsigned short*)hr;
#pragma unroll
    for (int rt=0; rt<2; ++rt)
#pragma unroll
    for (int q=0; q<16; ++q) acc[rt][q] = 0.0f;

    auto step = [&](int ksl, const short8 B){
      short8 Ah[2];
#pragma unroll
      for (int rt=0; rt<2; ++rt){
        const int r   = rt*32 + l31;
        const int off = (r << 9) + ((ksl*32 + kh*16) ^ ((r & 31) << 4));
        Ah[rt] = *(const short8*)(hr + off);
      }
#pragma unroll
      for (int rt=0; rt<2; ++rt)
        acc[rt] = __builtin_amdgcn_mfma_f32_32x32x16_bf16(Ah[rt], B, acc[rt], 0,0,0);
    };

    const int t0 = layer*16;
#pragma unroll
    for (int ks=0; ks<16; ks+=2){
      loadB(t0 + ks + 1, BB);
      step(ks, BA);
      loadB(min(t0 + ks + 2, 63), BA);
      step(ks + 1, BB);
    }

    // ---- repack S (acc, C-layout) into mix B-frags Bs[ks] (k = 16ks+8kh+j) ----
    // acc is fully dead after this block (16 bf16x8 regs replace 32 f32).
    short8 Bs[4];
#pragma unroll
    for (int ks=0; ks<4; ++ks){
      const int rt = ks >> 1;
      const int lq = ((2*ks) & 3) << 2;        // slots of rows 16ks+i (h0) / +4+i (h1)
      const int hq = ((2*ks + 1) & 3) << 2;    // slots of rows 16ks+8+i (h0) / +12+i (h1)
#pragma unroll
      for (int i=0; i<4; ++i){
        const float lo_v = acc[rt][lq | i];
        const float hi_v = acc[rt][hq | i];
        const float send = kh ? lo_v : hi_v;   // what partner half needs
        const float own  = kh ? hi_v : lo_v;   // what I keep
        const float recv = __shfl_xor(send, 32, 64);
        const float f_i  = kh ? recv : own;    // frag element j=i
        const float f_i4 = kh ? own  : recv;   // frag element j=4+i
        Bs[ks][i]     = (short)f2bf(f_i);
        Bs[ks][4 + i] = (short)f2bf(f_i4);
      }
    }

    // ---- mix MFMA: m2 = Ahat_bd @ S (single bf16 pass), fenced liveness ----
    float16 m2[2];
#pragma unroll
    for (int rt2=0; rt2<2; ++rt2)
#pragma unroll
    for (int q=0; q<16; ++q) m2[rt2][q] = 0.0f;
    __builtin_amdgcn_sched_barrier(0);
    const short8* al8 = (const short8*)al;
#pragma unroll
    for (int ks=0; ks<4; ++ks){
      {
        const short8 Am = al8[(0*4 + ks)*64 + lane];
        m2[0] = __builtin_amdgcn_mfma_f32_32x32x16_bf16(Am, Bs[ks], m2[0], 0,0,0);
      }
      __builtin_amdgcn_sched_barrier(0);
      {
        const short8 Am = al8[(1*4 + ks)*64 + lane];
        m2[1] = __builtin_amdgcn_mfma_f32_32x32x16_bf16(Am, Bs[ks], m2[1], 0,0,0);
      }
      __builtin_amdgcn_sched_barrier(0);
    }

    // ---- pointwise: h' = relu(m2 + bias) + h  (all slots, pad rows stay finite) ----
    {
      const float bsv = bs[layer*256 + c];
      unsigned short* hw = h + (((layer & 1) ^ 1) * RPAD*HID);
#pragma unroll
      for (int rt2=0; rt2<2; ++rt2)
#pragma unroll
      for (int q=0; q<16; ++q){
        const int r   = rt2*32 + (q&3) + 8*(q>>2) + 4*kh;
        const int off = (r << 9) + ((2*c) ^ ((r & 31) << 4));
        const float o = fmaxf(m2[rt2][q] + bsv, 0.0f) + bf2f(hru[off >> 1]);
        hw[off >> 1] = f2bf(o);
      }
    }
    __syncthreads();
  }

  // ---- output projection as MFMA on wave 0: y = h @ w_out + b_out ----
  if (wid == 0){
    const float bo = (l31 < 3) ? b_out[l31] : 0.0f;
    float16 y[2];
#pragma unroll
    for (int rt=0; rt<2; ++rt)
#pragma unroll
    for (int q=0; q<16; ++q) y[rt][q] = bo;

    const unsigned short* po = pret_out + kh*256 + l31*8;
#pragma unroll
    for (int ks=0; ks<16; ++ks){
      const short8 Bh = *(const short8*)(po + ks*512);
      const short8 Bl = *(const short8*)(po + 8192 + ks*512);
      short8 Ah[2];
#pragma unroll
      for (int rt=0; rt<2; ++rt){
        const int r   = rt*32 + l31;
        const int off = (r << 9) + ((ks*32 + kh*16) ^ ((r & 31) << 4));
        Ah[rt] = *(const short8*)(h_b + off);          // final h is buf0
      }
#pragma unroll
      for (int rt=0; rt<2; ++rt){
        y[rt] = __builtin_amdgcn_mfma_f32_32x32x16_bf16(Ah[rt], Bh, y[rt], 0,0,0);
        y[rt] = __builtin_amdgcn_mfma_f32_32x32x16_bf16(Ah[rt], Bl, y[rt], 0,0,0);
      }
    }
#pragma unroll
    for (int rt=0; rt<2; ++rt)
#pragma unroll
    for (int q=0; q<16; ++q){
      const int r0 = rt*32 + (q&3) + 8*(q>>2);
      const int r  = r0 + 4*kh;
      if (r < RUSE && l31 < 3){
        const int s = r/17, jj = r - s*17;
        out[((size_t)(wg*SPW + s)*17 + jj)*3 + l31] = y[rt][q];
      }
    }
  }
}

extern "C" void kernel_launch(void* const* d_in, const int* in_sizes, int n_in,
                              void* d_out, int out_size, void* d_ws, size_t ws_size,
                              hipStream_t stream)
{
  const float* x     = (const float*)d_in[0];
  const float* adj   = (const float*)d_in[1];
  const float* w_in  = (const float*)d_in[2];
  const float* b_in  = (const float*)d_in[3];
  const float* Ws    = (const float*)d_in[4];
  const float* bs    = (const float*)d_in[5];
  const float* w_out = (const float*)d_in[6];
  const float* b_out = (const float*)d_in[7];
  float* out = (float*)d_out;

  unsigned short* pret_a   = (unsigned short*)d_ws;                      // 8 KB
  unsigned short* pret_in  = (unsigned short*)((char*)d_ws + 8192);     // 8 KB
  unsigned short* pret_out = (unsigned short*)((char*)d_ws + 16384);    // 32 KB
  unsigned short* pret_b   = (unsigned short*)((char*)d_ws + 65536);    // 512 KB

  hipLaunchKernelGGL(gcn_prep, dim3(1025), dim3(256), 0, stream,
                     adj, Ws, w_in, w_out, pret_a, pret_in, pret_out, pret_b);
  hipLaunchKernelGGL(gcn_main, dim3(NWG), dim3(512), 0, stream,
                     x, b_in, bs, b_out, pret_a, pret_in, pret_out, pret_b, out);
}